// Round 2
// baseline (364.512 us; speedup 1.0000x reference)
//
#include <hip/hip_runtime.h>
#include <stdint.h>

#define NPIX 786432
#define KNB 9
#define CIN 16
#define COUT 16
#define NPAIR 8                      // CIN/2
#define WPAIRS (COUT * KNB * NPAIR)  // 1152

typedef _Float16 half2_t __attribute__((ext_vector_type(2)));
typedef uint32_t u32x4 __attribute__((ext_vector_type(4)));
typedef float    f32x4 __attribute__((ext_vector_type(4)));

__device__ __forceinline__ uint32_t packf16(float lo, float hi) {
    half2_t h;
    h[0] = (_Float16)lo;   // RNE convert
    h[1] = (_Float16)hi;
    return __builtin_bit_cast(uint32_t, h);
}
__device__ __forceinline__ half2_t ash2(uint32_t v) {
    return __builtin_bit_cast(half2_t, v);
}

// ---------------------------------------------------------------------------
// Pre-pass: x (2, NPIX, 16) fp32 -> xw (NPIX+1, 2, 16) f16 packed as 16 u32
// per pixel (batch0's 8 pairs then batch1's 8 pairs), explicit ZERO row at
// p == NPIX. Extra block packs w (16,9,16) fp32 -> 1152 u32 f16 pairs.
// ---------------------------------------------------------------------------
__global__ __launch_bounds__(256) void pack_kernel(
    const float* __restrict__ x, const float* __restrict__ w,
    uint32_t* __restrict__ xw, uint32_t* __restrict__ w2)
{
    const int xblocks = (NPIX + 1 + 255) / 256;  // 3073
    if ((int)blockIdx.x == xblocks) {
        for (int j = threadIdx.x; j < WPAIRS; j += 256)
            w2[j] = packf16(w[2 * j], w[2 * j + 1]);
        return;
    }
    const int p = blockIdx.x * 256 + threadIdx.x;
    if (p > NPIX) return;

    uint32_t v[16];
    if (p < NPIX) {
        const float4* __restrict__ r0 = (const float4*)(x + (size_t)p * CIN);
        const float4* __restrict__ r1 = (const float4*)(x + (size_t)NPIX * CIN + (size_t)p * CIN);
        const float4 a0 = r0[0], a1 = r0[1], a2 = r0[2], a3 = r0[3];
        const float4 b0 = r1[0], b1 = r1[1], b2 = r1[2], b3 = r1[3];
        v[0] = packf16(a0.x, a0.y); v[1] = packf16(a0.z, a0.w);
        v[2] = packf16(a1.x, a1.y); v[3] = packf16(a1.z, a1.w);
        v[4] = packf16(a2.x, a2.y); v[5] = packf16(a2.z, a2.w);
        v[6] = packf16(a3.x, a3.y); v[7] = packf16(a3.z, a3.w);
        v[8]  = packf16(b0.x, b0.y); v[9]  = packf16(b0.z, b0.w);
        v[10] = packf16(b1.x, b1.y); v[11] = packf16(b1.z, b1.w);
        v[12] = packf16(b2.x, b2.y); v[13] = packf16(b2.z, b2.w);
        v[14] = packf16(b3.x, b3.y); v[15] = packf16(b3.z, b3.w);
    } else {
#pragma unroll
        for (int i = 0; i < 16; ++i) v[i] = 0u;  // pad row = zeros
    }

    uint4* __restrict__ o = (uint4*)(xw + (size_t)p * 16);
    o[0] = make_uint4(v[0],  v[1],  v[2],  v[3]);
    o[1] = make_uint4(v[4],  v[5],  v[6],  v[7]);
    o[2] = make_uint4(v[8],  v[9],  v[10], v[11]);
    o[3] = make_uint4(v[12], v[13], v[14], v[15]);
}

// One k-step: 16 output channels x 8 f16-pair dots against row (q0,q1).
__device__ __forceinline__ void conv_step(
    int k, u32x4 q0, u32x4 q1, const uint32_t* __restrict__ w2, float* acc)
{
    const uint32_t xp[NPAIR] = {q0[0], q0[1], q0[2], q0[3],
                                q1[0], q1[1], q1[2], q1[3]};
    const uint32_t* __restrict__ wk = w2 + k * NPAIR;  // w2[o*72 + k*8 + j]
#pragma unroll
    for (int o = 0; o < COUT; ++o) {
        const uint32_t* __restrict__ wo = wk + o * (KNB * NPAIR);
        float a = acc[o];
#pragma unroll
        for (int j = 0; j < NPAIR; ++j)
            a = __builtin_amdgcn_fdot2(ash2(xp[j]), ash2(wo[j]), a, false);
        acc[o] = a;
    }
}

// ---------------------------------------------------------------------------
// Main: one thread per (pixel, batch). Lane pairs (2i,2i+1) share a pixel ->
// their 32 B halves of the same 64 B row coalesce.
//
// MLP is FORCED: all 18 gather loads (9 rows x 2 x 16 B) are issued before
// any compute, held live by an inline-asm value barrier (the compiler was
// sinking them: VGPR_Count=36 in the previous build => ~2 loads in flight,
// latency-bound at 3.6 TB/s). __launch_bounds__(256,4) caps VGPRs at 128
// (peak live ~110), giving 4 waves/SIMD with 18 KB in flight each.
// ---------------------------------------------------------------------------
__global__ __launch_bounds__(256, 4) void healpix_conv_kernel(
    const uint32_t* __restrict__ xw,
    const int* __restrict__ neigh,
    const uint32_t* __restrict__ w2,
    const float* __restrict__ bias,
    float* __restrict__ out)
{
    const int t  = blockIdx.x * 256 + threadIdx.x;  // [0, 2*NPIX)
    const int px = t >> 1;
    const int b  = t & 1;

    int idx[KNB];
#pragma unroll
    for (int k = 0; k < KNB; ++k) {
        int id = __builtin_nontemporal_load(&neigh[px * KNB + k]);
        id = id < 0 ? 0 : (id > NPIX ? NPIX : id);  // defensive clamp
        idx[k] = id;
    }

    const uint32_t* __restrict__ base = xw + b * NPAIR;  // batch half of row

#define ROWPTR(K) ((const u32x4*)(base + (size_t)idx[K] * 16))
    // All 9 gathers (18 x 16 B) in flight before any compute.
    const u32x4 r0a = ROWPTR(0)[0], r0b = ROWPTR(0)[1];
    const u32x4 r1a = ROWPTR(1)[0], r1b = ROWPTR(1)[1];
    const u32x4 r2a = ROWPTR(2)[0], r2b = ROWPTR(2)[1];
    const u32x4 r3a = ROWPTR(3)[0], r3b = ROWPTR(3)[1];
    const u32x4 r4a = ROWPTR(4)[0], r4b = ROWPTR(4)[1];
    const u32x4 r5a = ROWPTR(5)[0], r5b = ROWPTR(5)[1];
    const u32x4 r6a = ROWPTR(6)[0], r6b = ROWPTR(6)[1];
    const u32x4 r7a = ROWPTR(7)[0], r7b = ROWPTR(7)[1];
    const u32x4 r8a = ROWPTR(8)[0], r8b = ROWPTR(8)[1];
#undef ROWPTR

    // Value barrier: forces all 18 loads issued + completed HERE, all 72
    // data VGPRs simultaneously live. Defeats the compiler's load sinking.
    asm volatile(""
        :: "v"(r0a), "v"(r0b), "v"(r1a), "v"(r1b), "v"(r2a), "v"(r2b),
           "v"(r3a), "v"(r3b), "v"(r4a), "v"(r4b), "v"(r5a), "v"(r5b),
           "v"(r6a), "v"(r6b), "v"(r7a), "v"(r7b), "v"(r8a), "v"(r8b));

    float acc[COUT];
#pragma unroll
    for (int o = 0; o < COUT; ++o) acc[o] = bias[o];

    conv_step(0, r0a, r0b, w2, acc);
    conv_step(1, r1a, r1b, w2, acc);
    conv_step(2, r2a, r2b, w2, acc);
    conv_step(3, r3a, r3b, w2, acc);
    conv_step(4, r4a, r4b, w2, acc);
    conv_step(5, r5a, r5b, w2, acc);
    conv_step(6, r6a, r6b, w2, acc);
    conv_step(7, r7a, r7b, w2, acc);
    conv_step(8, r8a, r8b, w2, acc);

    // Output stores: nontemporal (native ext_vector type — HIP's float4 is a
    // class and the builtin rejects it). 100 MB stream must not evict xw.
    f32x4* __restrict__ op =
        (f32x4*)(out + (size_t)b * NPIX * COUT + (size_t)px * COUT);
    f32x4 o0 = {acc[0],  acc[1],  acc[2],  acc[3]};
    f32x4 o1 = {acc[4],  acc[5],  acc[6],  acc[7]};
    f32x4 o2 = {acc[8],  acc[9],  acc[10], acc[11]};
    f32x4 o3 = {acc[12], acc[13], acc[14], acc[15]};
    __builtin_nontemporal_store(o0, op + 0);
    __builtin_nontemporal_store(o1, op + 1);
    __builtin_nontemporal_store(o2, op + 2);
    __builtin_nontemporal_store(o3, op + 3);
}

extern "C" void kernel_launch(void* const* d_in, const int* in_sizes, int n_in,
                              void* d_out, int out_size, void* d_ws, size_t ws_size,
                              hipStream_t stream) {
    const float* x     = (const float*)d_in[0];
    const int*   neigh = (const int*)d_in[1];
    const float* w     = (const float*)d_in[2];
    const float* bias  = (const float*)d_in[3];
    float* out = (float*)d_out;

    uint32_t* xw = (uint32_t*)d_ws;                      // (NPIX+1)*16 u32 = 50.3 MB
    uint32_t* w2 = xw + (size_t)(NPIX + 1) * 16;         // 1152 u32

    const int xblocks = (NPIX + 1 + 255) / 256;          // 3073
    pack_kernel<<<xblocks + 1, 256, 0, stream>>>(x, w, xw, w2);

    const int conv_blocks = (2 * NPIX) / 256;            // 6144
    healpix_conv_kernel<<<conv_blocks, 256, 0, stream>>>(xw, neigh, w2, bias, out);
}

// Round 3
// 334.014 us; speedup vs baseline: 1.0913x; 1.0913x over previous
//
#include <hip/hip_runtime.h>
#include <stdint.h>

#define NPIX 786432
#define KNB 9
#define CIN 16
#define COUT 16
#define NPAIR 8                      // CIN/2
#define WPAIRS (COUT * KNB * NPAIR)  // 1152

typedef _Float16 half2_t __attribute__((ext_vector_type(2)));
typedef uint32_t u32x4 __attribute__((ext_vector_type(4)));

__device__ __forceinline__ uint32_t packf16(float lo, float hi) {
    half2_t h;
    h[0] = (_Float16)lo;   // RNE convert
    h[1] = (_Float16)hi;
    return __builtin_bit_cast(uint32_t, h);
}
__device__ __forceinline__ half2_t ash2(uint32_t v) {
    return __builtin_bit_cast(half2_t, v);
}

// ---------------------------------------------------------------------------
// Pre-pass: x (2, NPIX, 16) fp32 -> xw (NPIX+1, 2, 16) f16 packed as 16 u32
// per pixel (batch0's 8 pairs then batch1's 8 pairs), explicit ZERO row at
// p == NPIX. Extra block packs w (16,9,16) fp32 -> 1152 u32 f16 pairs.
// ---------------------------------------------------------------------------
__global__ __launch_bounds__(256) void pack_kernel(
    const float* __restrict__ x, const float* __restrict__ w,
    uint32_t* __restrict__ xw, uint32_t* __restrict__ w2)
{
    const int xblocks = (NPIX + 1 + 255) / 256;  // 3073
    if ((int)blockIdx.x == xblocks) {
        for (int j = threadIdx.x; j < WPAIRS; j += 256)
            w2[j] = packf16(w[2 * j], w[2 * j + 1]);
        return;
    }
    const int p = blockIdx.x * 256 + threadIdx.x;
    if (p > NPIX) return;

    uint32_t v[16];
    if (p < NPIX) {
        const float4* __restrict__ r0 = (const float4*)(x + (size_t)p * CIN);
        const float4* __restrict__ r1 = (const float4*)(x + (size_t)NPIX * CIN + (size_t)p * CIN);
        const float4 a0 = r0[0], a1 = r0[1], a2 = r0[2], a3 = r0[3];
        const float4 b0 = r1[0], b1 = r1[1], b2 = r1[2], b3 = r1[3];
        v[0] = packf16(a0.x, a0.y); v[1] = packf16(a0.z, a0.w);
        v[2] = packf16(a1.x, a1.y); v[3] = packf16(a1.z, a1.w);
        v[4] = packf16(a2.x, a2.y); v[5] = packf16(a2.z, a2.w);
        v[6] = packf16(a3.x, a3.y); v[7] = packf16(a3.z, a3.w);
        v[8]  = packf16(b0.x, b0.y); v[9]  = packf16(b0.z, b0.w);
        v[10] = packf16(b1.x, b1.y); v[11] = packf16(b1.z, b1.w);
        v[12] = packf16(b2.x, b2.y); v[13] = packf16(b2.z, b2.w);
        v[14] = packf16(b3.x, b3.y); v[15] = packf16(b3.z, b3.w);
    } else {
#pragma unroll
        for (int i = 0; i < 16; ++i) v[i] = 0u;  // pad row = zeros
    }

    uint4* __restrict__ o = (uint4*)(xw + (size_t)p * 16);
    o[0] = make_uint4(v[0],  v[1],  v[2],  v[3]);
    o[1] = make_uint4(v[4],  v[5],  v[6],  v[7]);
    o[2] = make_uint4(v[8],  v[9],  v[10], v[11]);
    o[3] = make_uint4(v[12], v[13], v[14], v[15]);
}

// One k-step: 16 output channels x 8 f16-pair dots against row (q0,q1).
__device__ __forceinline__ void conv_step(
    int k, u32x4 q0, u32x4 q1, const uint32_t* __restrict__ w2, float* acc)
{
    const uint32_t xp[NPAIR] = {q0[0], q0[1], q0[2], q0[3],
                                q1[0], q1[1], q1[2], q1[3]};
    const uint32_t* __restrict__ wk = w2 + k * NPAIR;  // w2[o*72 + k*8 + j]
#pragma unroll
    for (int o = 0; o < COUT; ++o) {
        const uint32_t* __restrict__ wo = wk + o * (KNB * NPAIR);
        float a = acc[o];
#pragma unroll
        for (int j = 0; j < NPAIR; ++j)
            a = __builtin_amdgcn_fdot2(ash2(xp[j]), ash2(wo[j]), a, false);
        acc[o] = a;
    }
}

// ---------------------------------------------------------------------------
// Main: one thread per (pixel, batch). Lane pairs (2i,2i+1) share a pixel ->
// their 32 B halves of the same 64 B row coalesce.
//
// MLP is forced with a MEMORY-CLOBBER barrier between the 18 gather loads
// and the compute. Round-2's input-only value pin was defeated by load
// rematerialization (all pointers are __restrict__, so re-loading for the
// asm while sinking the originals was legal -> VGPR_Count stayed 48 < 72).
// A may-write asm makes both sinking AND remat of the loads illegal: all
// 18 x 16 B loads must issue above it, the weight/bias loads below cannot
// hoist. 72 data VGPRs live -> ~110 peak, capped at 128 by
// __launch_bounds__(256,4): 4 waves/SIMD x 18 KB in flight per wave.
// ---------------------------------------------------------------------------
__global__ __launch_bounds__(256, 4) void healpix_conv_kernel(
    const uint32_t* __restrict__ xw,
    const int* __restrict__ neigh,
    const uint32_t* __restrict__ w2,
    const float* __restrict__ bias,
    float* __restrict__ out)
{
    const int t  = blockIdx.x * 256 + threadIdx.x;  // [0, 2*NPIX)
    const int px = t >> 1;
    const int b  = t & 1;

    int idx[KNB];
#pragma unroll
    for (int k = 0; k < KNB; ++k) {
        int id = neigh[px * KNB + k];
        id = id < 0 ? 0 : (id > NPIX ? NPIX : id);  // defensive clamp
        idx[k] = id;
    }

    const uint32_t* __restrict__ base = xw + b * NPAIR;  // batch half of row

#define ROWPTR(K) ((const u32x4*)(base + (size_t)idx[K] * 16))
    // All 9 gathers (18 x 16 B) issued before the barrier below.
    const u32x4 r0a = ROWPTR(0)[0], r0b = ROWPTR(0)[1];
    const u32x4 r1a = ROWPTR(1)[0], r1b = ROWPTR(1)[1];
    const u32x4 r2a = ROWPTR(2)[0], r2b = ROWPTR(2)[1];
    const u32x4 r3a = ROWPTR(3)[0], r3b = ROWPTR(3)[1];
    const u32x4 r4a = ROWPTR(4)[0], r4b = ROWPTR(4)[1];
    const u32x4 r5a = ROWPTR(5)[0], r5b = ROWPTR(5)[1];
    const u32x4 r6a = ROWPTR(6)[0], r6b = ROWPTR(6)[1];
    const u32x4 r7a = ROWPTR(7)[0], r7b = ROWPTR(7)[1];
    const u32x4 r8a = ROWPTR(8)[0], r8b = ROWPTR(8)[1];
#undef ROWPTR

    // Memory-clobber barrier: loads above may not sink past a may-write asm,
    // and may not be rematerialized below it. Weight/bias loads may not
    // hoist above it. This is what actually forces 18-deep MLP.
    asm volatile("" ::: "memory");

    float acc[COUT];
#pragma unroll
    for (int o = 0; o < COUT; ++o) acc[o] = bias[o];

    conv_step(0, r0a, r0b, w2, acc);
    conv_step(1, r1a, r1b, w2, acc);
    conv_step(2, r2a, r2b, w2, acc);
    conv_step(3, r3a, r3b, w2, acc);
    conv_step(4, r4a, r4b, w2, acc);
    conv_step(5, r5a, r5b, w2, acc);
    conv_step(6, r6a, r6b, w2, acc);
    conv_step(7, r7a, r7b, w2, acc);
    conv_step(8, r8a, r8b, w2, acc);

    float* __restrict__ op = out + (size_t)b * NPIX * COUT + (size_t)px * COUT;
    ((float4*)op)[0] = make_float4(acc[0],  acc[1],  acc[2],  acc[3]);
    ((float4*)op)[1] = make_float4(acc[4],  acc[5],  acc[6],  acc[7]);
    ((float4*)op)[2] = make_float4(acc[8],  acc[9],  acc[10], acc[11]);
    ((float4*)op)[3] = make_float4(acc[12], acc[13], acc[14], acc[15]);
}

extern "C" void kernel_launch(void* const* d_in, const int* in_sizes, int n_in,
                              void* d_out, int out_size, void* d_ws, size_t ws_size,
                              hipStream_t stream) {
    const float* x     = (const float*)d_in[0];
    const int*   neigh = (const int*)d_in[1];
    const float* w     = (const float*)d_in[2];
    const float* bias  = (const float*)d_in[3];
    float* out = (float*)d_out;

    uint32_t* xw = (uint32_t*)d_ws;                      // (NPIX+1)*16 u32 = 50.3 MB
    uint32_t* w2 = xw + (size_t)(NPIX + 1) * 16;         // 1152 u32

    const int xblocks = (NPIX + 1 + 255) / 256;          // 3073
    pack_kernel<<<xblocks + 1, 256, 0, stream>>>(x, w, xw, w2);

    const int conv_blocks = (2 * NPIX) / 256;            // 6144
    healpix_conv_kernel<<<conv_blocks, 256, 0, stream>>>(xw, neigh, w2, bias, out);
}